// Round 2
// baseline (862.068 us; speedup 1.0000x reference)
//
#include <hip/hip_runtime.h>
#include <hip/hip_bf16.h>
#include <type_traits>
#include <utility>

typedef unsigned short u16;
typedef __attribute__((ext_vector_type(8))) short  s16x8;
typedef __attribute__((ext_vector_type(4))) short  s16x4;
typedef __attribute__((ext_vector_type(4))) float  f32x4;
typedef __bf16 bf16x8_t __attribute__((ext_vector_type(8)));

#define SEQ 2048
#define DMODEL 2048
#define NBATCH 4
#define DH 128

static __device__ __forceinline__ u16 f2bf(float f) {
  unsigned u = __float_as_uint(f);
  u += 0x7fffu + ((u >> 16) & 1u);
  return (u16)(u >> 16);
}
static __device__ __forceinline__ float bf2f(u16 h) {
  return __uint_as_float(((unsigned)h) << 16);
}

// ---- MFMA wrapper: robust to short8 vs bf16x8 builtin signature ----
template <typename T, typename = void>
struct mfma_takes : std::false_type {};
template <typename T>
struct mfma_takes<T, std::void_t<decltype(__builtin_amdgcn_mfma_f32_16x16x32_bf16(
    std::declval<T>(), std::declval<T>(), std::declval<f32x4>(), 0, 0, 0))>>
    : std::true_type {};
using mfma_frag_t = std::conditional_t<mfma_takes<s16x8>::value, s16x8, bf16x8_t>;

static __device__ __forceinline__ f32x4 mfma16(s16x8 a, s16x8 b, f32x4 c) {
  return __builtin_amdgcn_mfma_f32_16x16x32_bf16(
      __builtin_bit_cast(mfma_frag_t, a), __builtin_bit_cast(mfma_frag_t, b), c, 0, 0, 0);
}

typedef const void __attribute__((address_space(1)))* gas_ptr;
typedef void __attribute__((address_space(3)))* las_ptr;
static __device__ __forceinline__ void gload16(const void* g, void* l) {
  __builtin_amdgcn_global_load_lds((gas_ptr)g, (las_ptr)l, 16, 0, 0);
}

// ---------------- f32 -> bf16 convert ----------------
__global__ void cvt_k(const float* __restrict__ in, u16* __restrict__ out, int n8) {
  const int stride = (int)(gridDim.x * blockDim.x);
  for (int i = (int)(blockIdx.x * blockDim.x + threadIdx.x); i < n8; i += stride) {
    const float4* p = (const float4*)in + (size_t)i * 2;
    float4 a = p[0], b4 = p[1];
    s16x8 o;
    o[0] = (short)f2bf(a.x);  o[1] = (short)f2bf(a.y);
    o[2] = (short)f2bf(a.z);  o[3] = (short)f2bf(a.w);
    o[4] = (short)f2bf(b4.x); o[5] = (short)f2bf(b4.y);
    o[6] = (short)f2bf(b4.z); o[7] = (short)f2bf(b4.w);
    *(s16x8*)(out + (size_t)i * 8) = o;
  }
}

// ---------------- GEMM: C[m,n] = sum_k A[m,k]*Bw[n,k] ----------------
// A: [8192][2048] bf16 row-major, Bw: [2048][2048] bf16 row-major.
// OUT_MODE 0: bf16 C[m][n];  1: f32 C[m][n];  2: bf16 C^T[n][m] (for V).
template <int OUT_MODE>
__global__ __launch_bounds__(256) void gemm_bt_k(const u16* __restrict__ A,
                                                 const u16* __restrict__ Bw,
                                                 void* __restrict__ Cv) {
  constexpr int M = 8192, N = 2048, K = 2048;
  __shared__ u16 As[128 * 64];
  __shared__ u16 Bs[128 * 64];
  const int tid = (int)threadIdx.x;
  const int w = tid >> 6, lane = tid & 63;
  const int l16 = lane & 15, lgrp = lane >> 4;
  const int wr = w >> 1, wc = w & 1;

  // XCD-aware swizzle (1024 wgs, divisible by 8 -> bijective)
  const int nwg = (int)gridDim.x;
  const int cpx = nwg >> 3;
  const int bid = (int)blockIdx.x;
  const int sb = (bid & 7) * cpx + (bid >> 3);
  const int bn = sb & 15;   // N/128 = 16
  const int bm = sb >> 4;

  const int srow = w * 32 + (lane >> 3);
  const int scol = (lane & 7) * 8;
  const u16* agp = A  + ((size_t)(bm * 128 + srow)) * K + scol;
  const u16* bgp = Bw + ((size_t)(bn * 128 + srow)) * K + scol;
  u16* alds = &As[w * 2048];
  u16* blds = &Bs[w * 2048];

  const f32x4 zero = {0.f, 0.f, 0.f, 0.f};
  f32x4 acc[4][4];
#pragma unroll
  for (int mi = 0; mi < 4; ++mi)
#pragma unroll
    for (int ni = 0; ni < 4; ++ni) acc[mi][ni] = zero;

  for (int kt = 0; kt < K; kt += 64) {
    __syncthreads();
#pragma unroll
    for (int i = 0; i < 4; ++i) {
      gload16(agp + kt + i * 8 * K, alds + i * 512);
      gload16(bgp + kt + i * 8 * K, blds + i * 512);
    }
    __syncthreads();
#pragma unroll
    for (int sl = 0; sl < 2; ++sl) {
      s16x8 af[4], bfr[4];
#pragma unroll
      for (int mi = 0; mi < 4; ++mi)
        af[mi] = *(const s16x8*)&As[(wr * 64 + mi * 16 + l16) * 64 + sl * 32 + lgrp * 8];
#pragma unroll
      for (int ni = 0; ni < 4; ++ni)
        bfr[ni] = *(const s16x8*)&Bs[(wc * 64 + ni * 16 + l16) * 64 + sl * 32 + lgrp * 8];
#pragma unroll
      for (int mi = 0; mi < 4; ++mi)
#pragma unroll
        for (int ni = 0; ni < 4; ++ni)
          acc[mi][ni] = mfma16(af[mi], bfr[ni], acc[mi][ni]);
    }
  }

  const size_t row0 = (size_t)bm * 128 + wr * 64;
  const size_t col0 = (size_t)bn * 128 + wc * 64;
#pragma unroll
  for (int mi = 0; mi < 4; ++mi)
#pragma unroll
    for (int ni = 0; ni < 4; ++ni) {
      const size_t r0 = row0 + mi * 16 + lgrp * 4;
      const size_t c  = col0 + ni * 16 + l16;
      if constexpr (OUT_MODE == 0) {
        u16* C = (u16*)Cv;
#pragma unroll
        for (int r = 0; r < 4; ++r) C[(r0 + r) * N + c] = f2bf(acc[mi][ni][r]);
      } else if constexpr (OUT_MODE == 1) {
        float* C = (float*)Cv;
#pragma unroll
        for (int r = 0; r < 4; ++r) C[(r0 + r) * N + c] = acc[mi][ni][r];
      } else {
        u16* C = (u16*)Cv;
        s16x4 v;
#pragma unroll
        for (int r = 0; r < 4; ++r) v[r] = (short)f2bf(acc[mi][ni][r]);
        *(s16x4*)&C[c * (size_t)M + r0] = v;  // C^T[n][m], 8B store
      }
    }
}

// ---------------- RoPE on q (first 512 dims), in place ----------------
__global__ void rope_k(u16* __restrict__ qb, const int* __restrict__ pos_ids) {
  const int row = (int)blockIdx.x;          // b*SEQ + s
  const int s = row & (SEQ - 1);
  const int t = (int)threadIdx.x;           // 0..255
  const float pos = (float)pos_ids[s];
  // inv_freq[t] = 10000^(-2t/512) = 2^(-t*log2(10000)/256)
  const float ang = pos * exp2f((float)t * (-13.287712379549449f / 256.0f));
  float sn, cs;
  sincosf(ang, &sn, &cs);
  u16* p = qb + (size_t)row * DMODEL;
  const float x = bf2f(p[t]);
  const float y = bf2f(p[t + 256]);
  p[t]       = f2bf(x * cs - y * sn);
  p[t + 256] = f2bf(y * cs + x * sn);
}

// ---------------- flash attention ----------------
// q,k: [B][S][2048] bf16 (head slice at g*128); vt: [2048][B*S] bf16 (V^T)
// att: [B][S][2048] bf16. One block = 64 q-rows of one (b,g); 4 waves.
__global__ __launch_bounds__(256) void attn_k(const u16* __restrict__ q,
                                              const u16* __restrict__ k,
                                              const u16* __restrict__ vt,
                                              const int* __restrict__ mask,
                                              u16* __restrict__ att) {
  __shared__ u16 Ks[64 * 128];      // [key][d], 256B rows, XOR-swizzled
  __shared__ u16 Vs[128 * 64];      // [d][key], 128B rows, XOR-swizzled
  __shared__ u16 Ps[4][16 * 64];    // per-wave P, 128B rows, XOR-swizzled

  const int tid = (int)threadIdx.x;
  const int w = tid >> 6, lane = tid & 63;
  const int l16 = lane & 15, lgrp = lane >> 4;

  const int bid = (int)blockIdx.x;
  const int sb = (bid & 7) * 256 + (bid >> 3);   // XCD swizzle (2048 wgs)
  const int qt = sb & 31;
  const int bg = sb >> 5;
  const int b = bg >> 4, g = bg & 15;

  // Q fragments, held in registers for the whole kernel
  const int qrow = qt * 64 + w * 16 + l16;
  const u16* qp = q + ((size_t)b * SEQ + qrow) * DMODEL + g * DH + lgrp * 8;
  s16x8 aq[4];
#pragma unroll
  for (int sl = 0; sl < 4; ++sl) aq[sl] = *(const s16x8*)(qp + sl * 32);

  const f32x4 zero = {0.f, 0.f, 0.f, 0.f};
  f32x4 oacc[8];
#pragma unroll
  for (int i = 0; i < 8; ++i) oacc[i] = zero;
  float mrow[4], lrow[4];
#pragma unroll
  for (int r = 0; r < 4; ++r) { mrow[r] = -1e30f; lrow[r] = 0.f; }

  const u16* kbase = k + (size_t)b * SEQ * DMODEL + g * DH;
  const u16* vbase = vt + (size_t)(g * DH) * (NBATCH * SEQ) + (size_t)b * SEQ;
  const int* mbase = mask + b * SEQ;
  const float scale = 0.08838834764831845f;   // 1/sqrt(128)

  for (int kt = 0; kt < SEQ; kt += 64) {
    __syncthreads();
    // stage K tile [64][128]: pre-swizzled global source, linear LDS dest
#pragma unroll
    for (int i = 0; i < 4; ++i) {
      const int row = w * 16 + i * 4 + lgrp;
      const int srcb = (l16 * 16) ^ ((row & 7) << 4);
      gload16(kbase + (size_t)(kt + row) * DMODEL + (srcb >> 1), &Ks[(w * 16 + i * 4) * 128]);
    }
    // stage V^T tile [128][64]
#pragma unroll
    for (int i = 0; i < 4; ++i) {
      const int row = w * 32 + i * 8 + (lane >> 3);
      const int srcb = ((lane & 7) * 16) ^ ((row & 7) << 4);
      gload16(vbase + (size_t)row * (NBATCH * SEQ) + kt + (srcb >> 1), &Vs[(w * 32 + i * 8) * 64]);
    }
    __syncthreads();

    const unsigned long long mbits = __ballot(mbase[kt + lane] != 0);

    // QK^T: S[16 q][64 key]
    f32x4 sacc[4];
#pragma unroll
    for (int kf = 0; kf < 4; ++kf) sacc[kf] = zero;
#pragma unroll
    for (int sl = 0; sl < 4; ++sl) {
#pragma unroll
      for (int kf = 0; kf < 4; ++kf) {
        const int row = kf * 16 + l16;
        const int colb = (sl * 64 + lgrp * 16) ^ ((row & 7) << 4);
        const s16x8 bk = *(const s16x8*)&Ks[row * 128 + (colb >> 1)];
        sacc[kf] = mfma16(aq[sl], bk, sacc[kf]);
      }
    }

    // online softmax; lane owns rows lgrp*4+r, key col = kf*16+l16
    float sv[4][4];
    float pmax[4];
#pragma unroll
    for (int r = 0; r < 4; ++r) pmax[r] = -1e30f;
#pragma unroll
    for (int kf = 0; kf < 4; ++kf) {
      const bool okm = (mbits >> (kf * 16 + l16)) & 1ull;
#pragma unroll
      for (int r = 0; r < 4; ++r) {
        const float s = okm ? sacc[kf][r] * scale : -1e30f;
        sv[kf][r] = s;
        pmax[r] = fmaxf(pmax[r], s);
      }
    }
#pragma unroll
    for (int off = 1; off < 16; off <<= 1)
#pragma unroll
      for (int r = 0; r < 4; ++r) pmax[r] = fmaxf(pmax[r], __shfl_xor(pmax[r], off, 64));

    float fac[4], psum[4];
#pragma unroll
    for (int r = 0; r < 4; ++r) {
      const float mnew = fmaxf(mrow[r], pmax[r]);
      fac[r] = __expf(mrow[r] - mnew);
      mrow[r] = mnew;
      psum[r] = 0.f;
    }
#pragma unroll
    for (int kf = 0; kf < 4; ++kf) {
#pragma unroll
      for (int r = 0; r < 4; ++r) {
        const float p = __expf(sv[kf][r] - mrow[r]);
        psum[r] += p;
        const int prow = lgrp * 4 + r;
        const int pcolb = ((kf * 16 + l16) * 2) ^ ((prow & 7) << 4);
        Ps[w][prow * 64 + (pcolb >> 1)] = f2bf(p);
      }
    }
#pragma unroll
    for (int off = 1; off < 16; off <<= 1)
#pragma unroll
      for (int r = 0; r < 4; ++r) psum[r] += __shfl_xor(psum[r], off, 64);
#pragma unroll
    for (int r = 0; r < 4; ++r) lrow[r] = lrow[r] * fac[r] + psum[r];
#pragma unroll
    for (int df = 0; df < 8; ++df)
#pragma unroll
      for (int r = 0; r < 4; ++r) oacc[df][r] *= fac[r];

    // PV: O[16 q][128 d] += P[16][64] @ V[64][128]
#pragma unroll
    for (int sl2 = 0; sl2 < 2; ++sl2) {
      const int pcolb = (sl2 * 64 + lgrp * 16) ^ ((l16 & 7) << 4);
      const s16x8 ap = *(const s16x8*)&Ps[w][l16 * 64 + (pcolb >> 1)];
#pragma unroll
      for (int df = 0; df < 8; ++df) {
        const int vrow = df * 16 + l16;
        const int vcolb = (sl2 * 64 + lgrp * 16) ^ ((vrow & 7) << 4);
        const s16x8 bv = *(const s16x8*)&Vs[vrow * 64 + (vcolb >> 1)];
        oacc[df] = mfma16(ap, bv, oacc[df]);
      }
    }
  }

  float inv[4];
#pragma unroll
  for (int r = 0; r < 4; ++r) inv[r] = 1.0f / lrow[r];
  u16* ob = att + ((size_t)b * SEQ + qt * 64 + w * 16 + lgrp * 4) * DMODEL + g * DH + l16;
#pragma unroll
  for (int df = 0; df < 8; ++df)
#pragma unroll
    for (int r = 0; r < 4; ++r)
      ob[(size_t)r * DMODEL + df * 16] = f2bf(oacc[df][r] * inv[r]);
}

// ---------------- launch ----------------
extern "C" void kernel_launch(void* const* d_in, const int* in_sizes, int n_in,
                              void* d_out, int out_size, void* d_ws, size_t ws_size,
                              hipStream_t stream) {
  const float* query = (const float*)d_in[0];
  const float* key   = (const float*)d_in[1];
  const float* value = (const float*)d_in[2];
  const int*   maskp = (const int*)d_in[3];
  const int*   posp  = (const int*)d_in[4];
  const float* Wq    = (const float*)d_in[5];
  const float* Wk    = (const float*)d_in[6];
  const float* Wv    = (const float*)d_in[7];
  const float* Wo    = (const float*)d_in[8];

  char* ws = (char*)d_ws;
  const size_t MB = 1024ull * 1024ull;
  u16* wq_b = (u16*)(ws + 0 * MB);     // 8 MiB each
  u16* wk_b = (u16*)(ws + 8 * MB);
  u16* wv_b = (u16*)(ws + 16 * MB);
  u16* wo_b = (u16*)(ws + 24 * MB);
  u16* xq   = (u16*)(ws + 32 * MB);    // 32 MiB each
  u16* xk   = (u16*)(ws + 64 * MB);
  u16* xv   = (u16*)(ws + 96 * MB);
  u16* qb   = (u16*)(ws + 128 * MB);
  u16* kb   = (u16*)(ws + 160 * MB);
  u16* vtb  = (u16*)(ws + 192 * MB);
  u16* att  = xq;                      // reuse: xq dead after q-projection

  const int nTok8 = (NBATCH * SEQ * DMODEL) / 8;  // 2,097,152
  const int nW8   = (DMODEL * DMODEL) / 8;        // 524,288
  cvt_k<<<dim3(2048), dim3(256), 0, stream>>>(query, xq, nTok8);
  cvt_k<<<dim3(2048), dim3(256), 0, stream>>>(key,   xk, nTok8);
  cvt_k<<<dim3(2048), dim3(256), 0, stream>>>(value, xv, nTok8);
  cvt_k<<<dim3(2048), dim3(256), 0, stream>>>(Wq, wq_b, nW8);
  cvt_k<<<dim3(2048), dim3(256), 0, stream>>>(Wk, wk_b, nW8);
  cvt_k<<<dim3(2048), dim3(256), 0, stream>>>(Wv, wv_b, nW8);
  cvt_k<<<dim3(2048), dim3(256), 0, stream>>>(Wo, wo_b, nW8);

  gemm_bt_k<0><<<dim3(1024), dim3(256), 0, stream>>>(xq, wq_b, (void*)qb);
  gemm_bt_k<0><<<dim3(1024), dim3(256), 0, stream>>>(xk, wk_b, (void*)kb);
  gemm_bt_k<2><<<dim3(1024), dim3(256), 0, stream>>>(xv, wv_b, (void*)vtb);

  rope_k<<<dim3(NBATCH * SEQ), dim3(256), 0, stream>>>(qb, posp);

  attn_k<<<dim3(2048), dim3(256), 0, stream>>>(qb, kb, vtb, maskp, att);

  gemm_bt_k<1><<<dim3(1024), dim3(256), 0, stream>>>(att, wo_b, d_out);

  (void)in_sizes; (void)n_in; (void)out_size; (void)ws_size;
}

// Round 3
// 801.555 us; speedup vs baseline: 1.0755x; 1.0755x over previous
//
#include <hip/hip_runtime.h>
#include <hip/hip_bf16.h>
#include <type_traits>
#include <utility>

typedef unsigned short u16;
typedef unsigned int u32;
typedef __attribute__((ext_vector_type(8))) short  s16x8;
typedef __attribute__((ext_vector_type(4))) short  s16x4;
typedef __attribute__((ext_vector_type(4))) float  f32x4;
typedef __attribute__((ext_vector_type(16))) float f32x16;
typedef __bf16 bf16x8_t __attribute__((ext_vector_type(8)));
typedef __bf16 bf16x2_t __attribute__((ext_vector_type(2)));

#define SEQ 2048
#define DMODEL 2048
#define NBATCH 4
#define DH 128
#define NB (NBATCH * SEQ)

// Q pre-scale: (1/sqrt(128)) * log2(e)  -> scores come out in log2 domain
#define QK_SCALE_LOG2 0.12754375f
// bias constants (log2 domain): valid = -24*log2e ; masked = huge negative
#define BIAS_VALID  (-34.624681f)
#define BIAS_MASKED (-180.0f)

static __device__ __forceinline__ u16 f2bf(float f) {
  unsigned u = __float_as_uint(f);
  u += 0x7fffu + ((u >> 16) & 1u);
  return (u16)(u >> 16);
}
static __device__ __forceinline__ float bf2f(u16 h) {
  return __uint_as_float(((unsigned)h) << 16);
}
static __device__ __forceinline__ u32 pack_bf16(float a, float b) {
  bf16x2_t t; t[0] = (__bf16)a; t[1] = (__bf16)b;
  return __builtin_bit_cast(u32, t);
}

// ---- MFMA wrappers: robust to short8 vs bf16x8 builtin signature ----
template <typename T, typename = void>
struct mfma_takes : std::false_type {};
template <typename T>
struct mfma_takes<T, std::void_t<decltype(__builtin_amdgcn_mfma_f32_16x16x32_bf16(
    std::declval<T>(), std::declval<T>(), std::declval<f32x4>(), 0, 0, 0))>>
    : std::true_type {};
using mfma_frag_t = std::conditional_t<mfma_takes<s16x8>::value, s16x8, bf16x8_t>;

static __device__ __forceinline__ f32x4 mfma16(s16x8 a, s16x8 b, f32x4 c) {
  return __builtin_amdgcn_mfma_f32_16x16x32_bf16(
      __builtin_bit_cast(mfma_frag_t, a), __builtin_bit_cast(mfma_frag_t, b), c, 0, 0, 0);
}
static __device__ __forceinline__ f32x16 mfma32(s16x8 a, s16x8 b, f32x16 c) {
  return __builtin_amdgcn_mfma_f32_32x32x16_bf16(
      __builtin_bit_cast(mfma_frag_t, a), __builtin_bit_cast(mfma_frag_t, b), c, 0, 0, 0);
}

typedef const void __attribute__((address_space(1)))* gas_ptr;
typedef void __attribute__((address_space(3)))* las_ptr;
static __device__ __forceinline__ void gload16(const void* g, void* l) {
  __builtin_amdgcn_global_load_lds((gas_ptr)g, (las_ptr)l, 16, 0, 0);
}

static __device__ __forceinline__ s16x8 frag_from_words(u32 w0, u32 w1, u32 w2, u32 w3) {
  union { u32 w[4]; s16x8 v; } u;
  u.w[0] = w0; u.w[1] = w1; u.w[2] = w2; u.w[3] = w3;
  return u.v;
}

// ---------------- f32 -> bf16 convert ----------------
__global__ void cvt_k(const float* __restrict__ in, u16* __restrict__ out, int n8) {
  const int stride = (int)(gridDim.x * blockDim.x);
  for (int i = (int)(blockIdx.x * blockDim.x + threadIdx.x); i < n8; i += stride) {
    const float4* p = (const float4*)in + (size_t)i * 2;
    float4 a = p[0], b4 = p[1];
    s16x8 o;
    o[0] = (short)f2bf(a.x);  o[1] = (short)f2bf(a.y);
    o[2] = (short)f2bf(a.z);  o[3] = (short)f2bf(a.w);
    o[4] = (short)f2bf(b4.x); o[5] = (short)f2bf(b4.y);
    o[6] = (short)f2bf(b4.z); o[7] = (short)f2bf(b4.w);
    *(s16x8*)(out + (size_t)i * 8) = o;
  }
}

// ---------------- mask -> bias (bf16, log2 domain) ----------------
__global__ void bias_k(const int* __restrict__ mask, u16* __restrict__ biasv, int n) {
  const int i = (int)(blockIdx.x * blockDim.x + threadIdx.x);
  if (i < n) biasv[i] = mask[i] ? f2bf(BIAS_VALID) : f2bf(BIAS_MASKED);
}

// ---------------- GEMM: C[m,n] = sum_k A[m,k]*Bw[n,k] ----------------
template <int OUT_MODE>
__global__ __launch_bounds__(256) void gemm_bt_k(const u16* __restrict__ A,
                                                 const u16* __restrict__ Bw,
                                                 void* __restrict__ Cv) {
  constexpr int M = 8192, N = 2048, K = 2048;
  __shared__ u16 As[128 * 64];
  __shared__ u16 Bs[128 * 64];
  const int tid = (int)threadIdx.x;
  const int w = tid >> 6, lane = tid & 63;
  const int l16 = lane & 15, lgrp = lane >> 4;
  const int wr = w >> 1, wc = w & 1;

  const int nwg = (int)gridDim.x;
  const int cpx = nwg >> 3;
  const int bid = (int)blockIdx.x;
  const int sb = (bid & 7) * cpx + (bid >> 3);
  const int bn = sb & 15;
  const int bm = sb >> 4;

  const int srow = w * 32 + (lane >> 3);
  const int scol = (lane & 7) * 8;
  const u16* agp = A  + ((size_t)(bm * 128 + srow)) * K + scol;
  const u16* bgp = Bw + ((size_t)(bn * 128 + srow)) * K + scol;
  u16* alds = &As[w * 2048];
  u16* blds = &Bs[w * 2048];

  const f32x4 zero = {0.f, 0.f, 0.f, 0.f};
  f32x4 acc[4][4];
#pragma unroll
  for (int mi = 0; mi < 4; ++mi)
#pragma unroll
    for (int ni = 0; ni < 4; ++ni) acc[mi][ni] = zero;

  for (int kt = 0; kt < K; kt += 64) {
    __syncthreads();
#pragma unroll
    for (int i = 0; i < 4; ++i) {
      gload16(agp + kt + i * 8 * K, alds + i * 512);
      gload16(bgp + kt + i * 8 * K, blds + i * 512);
    }
    __syncthreads();
#pragma unroll
    for (int sl = 0; sl < 2; ++sl) {
      s16x8 af[4], bfr[4];
#pragma unroll
      for (int mi = 0; mi < 4; ++mi)
        af[mi] = *(const s16x8*)&As[(wr * 64 + mi * 16 + l16) * 64 + sl * 32 + lgrp * 8];
#pragma unroll
      for (int ni = 0; ni < 4; ++ni)
        bfr[ni] = *(const s16x8*)&Bs[(wc * 64 + ni * 16 + l16) * 64 + sl * 32 + lgrp * 8];
#pragma unroll
      for (int mi = 0; mi < 4; ++mi)
#pragma unroll
        for (int ni = 0; ni < 4; ++ni)
          acc[mi][ni] = mfma16(af[mi], bfr[ni], acc[mi][ni]);
    }
  }

  const size_t row0 = (size_t)bm * 128 + wr * 64;
  const size_t col0 = (size_t)bn * 128 + wc * 64;
#pragma unroll
  for (int mi = 0; mi < 4; ++mi)
#pragma unroll
    for (int ni = 0; ni < 4; ++ni) {
      const size_t r0 = row0 + mi * 16 + lgrp * 4;
      const size_t c  = col0 + ni * 16 + l16;
      if constexpr (OUT_MODE == 0) {
        u16* C = (u16*)Cv;
#pragma unroll
        for (int r = 0; r < 4; ++r) C[(r0 + r) * N + c] = f2bf(acc[mi][ni][r]);
      } else if constexpr (OUT_MODE == 1) {
        float* C = (float*)Cv;
#pragma unroll
        for (int r = 0; r < 4; ++r) C[(r0 + r) * N + c] = acc[mi][ni][r];
      } else {
        u16* C = (u16*)Cv;
        s16x4 v;
#pragma unroll
        for (int r = 0; r < 4; ++r) v[r] = (short)f2bf(acc[mi][ni][r]);
        *(s16x4*)&C[c * (size_t)M + r0] = v;
      }
    }
}

// -------- RoPE on q (first 512 dims) + global scale by QK_SCALE_LOG2 --------
__global__ void rope_k(u16* __restrict__ qb, const int* __restrict__ pos_ids) {
  const int row = (int)blockIdx.x;          // b*SEQ + s
  const int s = row & (SEQ - 1);
  const int t = (int)threadIdx.x;           // 0..255
  const float pos = (float)pos_ids[s];
  const float ang = pos * exp2f((float)t * (-13.287712379549449f / 256.0f));
  float sn, cs;
  sincosf(ang, &sn, &cs);
  u16* p = qb + (size_t)row * DMODEL;
  const float x = bf2f(p[t]);
  const float y = bf2f(p[t + 256]);
  p[t]       = f2bf((x * cs - y * sn) * QK_SCALE_LOG2);
  p[t + 256] = f2bf((y * cs + x * sn) * QK_SCALE_LOG2);
#pragma unroll
  for (int j = 0; j < 6; ++j) {
    const int d = 512 + t + 256 * j;
    p[d] = f2bf(bf2f(p[d]) * QK_SCALE_LOG2);
  }
}

// ---------------- flash attention, 32x32 swapped structure ----------------
// q (pre-scaled), k: [B][S][2048] bf16; vt: [2048][NB] bf16 (V^T);
// biasv: [B][S] bf16 (log2-domain, -inf-ish for masked); att: [B][S][2048] bf16.
// One block = 128 q-rows of one (b,g); 4 waves x 32 q-rows.
__device__ __forceinline__ void attn_stage(u16* Ks, u16* Vs,
                                           const u16* kbase, const u16* vbase,
                                           int kt, int w, int lane) {
#pragma unroll
  for (int i = 0; i < 4; ++i) {   // K tile [64][128], 256B rows, XOR-swizzled
    const int row = w * 16 + i * 4 + (lane >> 4);
    const int srcb = ((lane & 15) * 16) ^ ((row & 7) << 4);
    gload16(kbase + (size_t)(kt + row) * DMODEL + (srcb >> 1), &Ks[(w * 16 + i * 4) * 128]);
  }
#pragma unroll
  for (int i = 0; i < 4; ++i) {   // V^T tile [128][64], 128B rows, XOR-swizzled
    const int row = w * 32 + i * 8 + (lane >> 3);
    const int srcb = ((lane & 7) * 16) ^ ((row & 7) << 4);
    gload16(vbase + (size_t)row * NB + kt + (srcb >> 1), &Vs[(w * 32 + i * 8) * 64]);
  }
}

__global__ __launch_bounds__(256) void attn_k(const u16* __restrict__ q,
                                              const u16* __restrict__ k,
                                              const u16* __restrict__ vt,
                                              const u16* __restrict__ biasv,
                                              u16* __restrict__ att) {
  __shared__ u16 Ks[2][64 * 128];
  __shared__ u16 Vs[2][128 * 64];

  const int tid = (int)threadIdx.x;
  const int w = tid >> 6, lane = tid & 63;
  const int l32 = lane & 31, hi = lane >> 5;

  const int bid = (int)blockIdx.x;
  const int sb = (bid & 7) * 128 + (bid >> 3);   // XCD swizzle (1024 wgs)
  const int qt = sb & 15;                         // 2048/128 q-tiles
  const int bg = sb >> 4;
  const int b = bg >> 4, g = bg & 15;

  // Q fragments (B-operand): B[col=q=l32][k=d slice], 8 steps of 16 d
  const int qrow = qt * 128 + w * 32 + l32;
  const u16* qp = q + ((size_t)b * SEQ + qrow) * DMODEL + g * DH;
  s16x8 aq[8];
#pragma unroll
  for (int s = 0; s < 8; ++s) aq[s] = *(const s16x8*)(qp + s * 16 + hi * 8);

  // constant fragments
  const u32 one0 = (hi == 0) ? 0x00003F80u : 0u;
  const s16x8 bones = frag_from_words(one0, 0, 0, 0);            // B: ones at k=0
  const s16x8 allones = frag_from_words(0x3F803F80u, 0x3F803F80u, 0x3F803F80u, 0x3F803F80u);

  f32x16 oacc[4], lacc;
#pragma unroll
  for (int r = 0; r < 16; ++r) {
    lacc[r] = 0.f;
#pragma unroll
    for (int d0 = 0; d0 < 4; ++d0) oacc[d0][r] = 0.f;
  }

  const u16* kbase = k + (size_t)b * SEQ * DMODEL + g * DH;
  const u16* vbase = vt + (size_t)(g * DH) * NB + (size_t)b * SEQ;
  const u16* bbase = biasv + b * SEQ;

  attn_stage(Ks[0], Vs[0], kbase, vbase, 0, w, lane);
  u16 bb0 = bbase[l32], bb1 = bbase[32 + l32];

  for (int t = 0; t < 32; ++t) {
    const int cur = t & 1;
    __syncthreads();   // compiler drains vmcnt here -> tile t ready
    u16 bbn0 = bb0, bbn1 = bb1;
    if (t < 31) {
      attn_stage(Ks[cur ^ 1], Vs[cur ^ 1], kbase, vbase, (t + 1) * 64, w, lane);
      bbn0 = bbase[(t + 1) * 64 + l32];
      bbn1 = bbase[(t + 1) * 64 + 32 + l32];
    }
    const u16* KsC = Ks[cur];
    const u16* VsC = Vs[cur];

    // score init via bias MFMA: sacc[key][q] = bias[key]
    const s16x8 ab0 = frag_from_words((hi == 0) ? (u32)bb0 : 0u, 0, 0, 0);
    const s16x8 ab1 = frag_from_words((hi == 0) ? (u32)bb1 : 0u, 0, 0, 0);
    f32x16 sacc0 = mfma32(ab0, bones, (f32x16)(0.f));
    f32x16 sacc1 = mfma32(ab1, bones, (f32x16)(0.f));

    // QK^T swapped: A=K (row=key), B=Q (col=q)
#pragma unroll
    for (int s = 0; s < 8; ++s) {
      const int byteoff = ((s * 32 + hi * 16) ^ ((l32 & 7) << 4)) >> 1;
      const s16x8 a0 = *(const s16x8*)&KsC[l32 * 128 + byteoff];
      const s16x8 a1 = *(const s16x8*)&KsC[(32 + l32) * 128 + byteoff];
      sacc0 = mfma32(a0, aq[s], sacc0);
      sacc1 = mfma32(a1, aq[s], sacc1);
    }

    // p = exp2(sacc); pack to bf16 pairs (consecutive keys = consecutive regs)
    u32 pk0[8], pk1[8];
#pragma unroll
    for (int i = 0; i < 8; ++i) {
      pk0[i] = pack_bf16(exp2f(sacc0[2 * i]), exp2f(sacc0[2 * i + 1]));
      pk1[i] = pack_bf16(exp2f(sacc1[2 * i]), exp2f(sacc1[2 * i + 1]));
    }
    u32 rk0[8], rk1[8];
#pragma unroll
    for (int i = 0; i < 8; ++i) {
      rk0[i] = (u32)__shfl_xor((int)pk0[i], 32, 64);
      rk1[i] = (u32)__shfl_xor((int)pk1[i], 32, 64);
    }
    // build P A-frags: pa[ks] = P[q=l32][key = ks*16 + hi*8 + j]
    s16x8 pa[4];
#pragma unroll
    for (int ks = 0; ks < 4; ++ks) {
      const u32* X = (ks < 2) ? pk0 : pk1;
      const u32* R = (ks < 2) ? rk0 : rk1;
      const int k4 = 4 * (ks & 1);
      const u32 w0 = hi ? R[k4 + 2] : X[k4 + 0];
      const u32 w1 = hi ? R[k4 + 3] : X[k4 + 1];
      const u32 w2 = hi ? X[k4 + 2] : R[k4 + 0];
      const u32 w3 = hi ? X[k4 + 3] : R[k4 + 1];
      pa[ks] = frag_from_words(w0, w1, w2, w3);
    }

    // row sums via MFMA with all-ones B (same C layout as oacc)
#pragma unroll
    for (int ks = 0; ks < 4; ++ks) lacc = mfma32(pa[ks], allones, lacc);

    // PV: O[q][d] += P[q][key] @ V[key][d]; B from V^T rows (d), 8 keys each
#pragma unroll
    for (int d0 = 0; d0 < 4; ++d0) {
      const int rowd = d0 * 32 + l32;
#pragma unroll
      for (int ks = 0; ks < 4; ++ks) {
        const int byteoff = ((ks * 32 + hi * 16) ^ ((l32 & 7) << 4)) >> 1;
        const s16x8 bv = *(const s16x8*)&VsC[rowd * 64 + byteoff];
        oacc[d0] = mfma32(pa[ks], bv, oacc[d0]);
      }
    }
    bb0 = bbn0; bb1 = bbn1;
  }

  // epilogue: normalize and store
  float rinv[16];
#pragma unroll
  for (int r = 0; r < 16; ++r) rinv[r] = 1.0f / lacc[r];
  u16* ob = att + ((size_t)b * SEQ + qt * 128 + w * 32) * DMODEL + g * DH;
#pragma unroll
  for (int d0 = 0; d0 < 4; ++d0)
#pragma unroll
    for (int r = 0; r < 16; ++r) {
      const int qloc = (r & 3) + 8 * (r >> 2) + 4 * hi;
      ob[(size_t)qloc * DMODEL + d0 * 32 + l32] = f2bf(oacc[d0][r] * rinv[r]);
    }
}

// ---------------- launch ----------------
extern "C" void kernel_launch(void* const* d_in, const int* in_sizes, int n_in,
                              void* d_out, int out_size, void* d_ws, size_t ws_size,
                              hipStream_t stream) {
  const float* query = (const float*)d_in[0];
  const float* key   = (const float*)d_in[1];
  const float* value = (const float*)d_in[2];
  const int*   maskp = (const int*)d_in[3];
  const int*   posp  = (const int*)d_in[4];
  const float* Wq    = (const float*)d_in[5];
  const float* Wk    = (const float*)d_in[6];
  const float* Wv    = (const float*)d_in[7];
  const float* Wo    = (const float*)d_in[8];

  char* ws = (char*)d_ws;
  const size_t MB = 1024ull * 1024ull;
  u16* wq_b = (u16*)(ws + 0 * MB);
  u16* wk_b = (u16*)(ws + 8 * MB);
  u16* wv_b = (u16*)(ws + 16 * MB);
  u16* wo_b = (u16*)(ws + 24 * MB);
  u16* xq   = (u16*)(ws + 32 * MB);
  u16* xk   = (u16*)(ws + 64 * MB);
  u16* xv   = (u16*)(ws + 96 * MB);
  u16* qb   = (u16*)(ws + 128 * MB);
  u16* kb   = (u16*)(ws + 160 * MB);
  u16* vtb  = (u16*)(ws + 192 * MB);
  u16* att  = xq;                       // xq dead after q-projection
  u16* biasv = xk;                      // xk dead after k-projection

  const int nTok8 = (NBATCH * SEQ * DMODEL) / 8;
  const int nW8   = (DMODEL * DMODEL) / 8;
  cvt_k<<<dim3(2048), dim3(256), 0, stream>>>(query, xq, nTok8);
  cvt_k<<<dim3(2048), dim3(256), 0, stream>>>(key,   xk, nTok8);
  cvt_k<<<dim3(2048), dim3(256), 0, stream>>>(value, xv, nTok8);
  cvt_k<<<dim3(2048), dim3(256), 0, stream>>>(Wq, wq_b, nW8);
  cvt_k<<<dim3(2048), dim3(256), 0, stream>>>(Wk, wk_b, nW8);
  cvt_k<<<dim3(2048), dim3(256), 0, stream>>>(Wv, wv_b, nW8);
  cvt_k<<<dim3(2048), dim3(256), 0, stream>>>(Wo, wo_b, nW8);

  gemm_bt_k<0><<<dim3(1024), dim3(256), 0, stream>>>(xq, wq_b, (void*)qb);
  gemm_bt_k<0><<<dim3(1024), dim3(256), 0, stream>>>(xk, wk_b, (void*)kb);
  gemm_bt_k<2><<<dim3(1024), dim3(256), 0, stream>>>(xv, wv_b, (void*)vtb);

  // xk is dead now: build bias table in its place
  bias_k<<<dim3((NBATCH * SEQ + 255) / 256), dim3(256), 0, stream>>>(maskp, biasv, NBATCH * SEQ);

  rope_k<<<dim3(NBATCH * SEQ), dim3(256), 0, stream>>>(qb, posp);

  attn_k<<<dim3(1024), dim3(256), 0, stream>>>(qb, kb, vtb, biasv, att);

  gemm_bt_k<1><<<dim3(1024), dim3(256), 0, stream>>>(att, wo_b, d_out);

  (void)in_sizes; (void)n_in; (void)out_size; (void)ws_size;
}

// Round 4
// 723.229 us; speedup vs baseline: 1.1920x; 1.1083x over previous
//
#include <hip/hip_runtime.h>
#include <hip/hip_bf16.h>
#include <type_traits>
#include <utility>

typedef unsigned short u16;
typedef unsigned int u32;
typedef __attribute__((ext_vector_type(8))) short  s16x8;
typedef __attribute__((ext_vector_type(4))) short  s16x4;
typedef __attribute__((ext_vector_type(4))) float  f32x4;
typedef __attribute__((ext_vector_type(16))) float f32x16;
typedef __bf16 bf16x8_t __attribute__((ext_vector_type(8)));
typedef __bf16 bf16x2_t __attribute__((ext_vector_type(2)));

#define SEQ 2048
#define DMODEL 2048
#define NBATCH 4
#define DH 128
#define NB (NBATCH * SEQ)

// Q pre-scale: (1/sqrt(128)) * log2(e)  -> scores come out in log2 domain
#define QK_SCALE_LOG2 0.12754375f
// bias constants (log2 domain): valid = -24*log2e ; masked = huge negative
#define BIAS_VALID  (-34.624681f)
#define BIAS_MASKED (-180.0f)

#if __has_builtin(__builtin_amdgcn_exp2f)
#define EXP2(x) __builtin_amdgcn_exp2f(x)
#else
#define EXP2(x) exp2f(x)
#endif

static __device__ __forceinline__ u16 f2bf(float f) {
  unsigned u = __float_as_uint(f);
  u += 0x7fffu + ((u >> 16) & 1u);
  return (u16)(u >> 16);
}
static __device__ __forceinline__ float bf2f(u16 h) {
  return __uint_as_float(((unsigned)h) << 16);
}
static __device__ __forceinline__ u32 pack_bf16(float a, float b) {
  bf16x2_t t; t[0] = (__bf16)a; t[1] = (__bf16)b;
  return __builtin_bit_cast(u32, t);
}
// v_permlane32_swap_b32: after the op, a = {a.row0, b.row0}, b = {a.row1, b.row1}
// (row0 = lanes 0-31, row1 = lanes 32-63). Derived to match the verified T12 recipe.
static __device__ __forceinline__ void plswap(u32& a, u32& b) {
  asm("v_permlane32_swap_b32 %0, %1" : "+v"(a), "+v"(b));
}

// ---- MFMA wrappers: robust to short8 vs bf16x8 builtin signature ----
template <typename T, typename = void>
struct mfma_takes : std::false_type {};
template <typename T>
struct mfma_takes<T, std::void_t<decltype(__builtin_amdgcn_mfma_f32_16x16x32_bf16(
    std::declval<T>(), std::declval<T>(), std::declval<f32x4>(), 0, 0, 0))>>
    : std::true_type {};
using mfma_frag_t = std::conditional_t<mfma_takes<s16x8>::value, s16x8, bf16x8_t>;

static __device__ __forceinline__ f32x4 mfma16(s16x8 a, s16x8 b, f32x4 c) {
  return __builtin_amdgcn_mfma_f32_16x16x32_bf16(
      __builtin_bit_cast(mfma_frag_t, a), __builtin_bit_cast(mfma_frag_t, b), c, 0, 0, 0);
}
static __device__ __forceinline__ f32x16 mfma32(s16x8 a, s16x8 b, f32x16 c) {
  return __builtin_amdgcn_mfma_f32_32x32x16_bf16(
      __builtin_bit_cast(mfma_frag_t, a), __builtin_bit_cast(mfma_frag_t, b), c, 0, 0, 0);
}

typedef const void __attribute__((address_space(1)))* gas_ptr;
typedef void __attribute__((address_space(3)))* las_ptr;
static __device__ __forceinline__ void gload16(const void* g, void* l) {
  __builtin_amdgcn_global_load_lds((gas_ptr)g, (las_ptr)l, 16, 0, 0);
}

static __device__ __forceinline__ s16x8 frag_from_words(u32 w0, u32 w1, u32 w2, u32 w3) {
  union { u32 w[4]; s16x8 v; } u;
  u.w[0] = w0; u.w[1] = w1; u.w[2] = w2; u.w[3] = w3;
  return u.v;
}

// ---------------- f32 -> bf16 convert ----------------
__global__ void cvt_k(const float* __restrict__ in, u16* __restrict__ out, int n8) {
  const int stride = (int)(gridDim.x * blockDim.x);
  for (int i = (int)(blockIdx.x * blockDim.x + threadIdx.x); i < n8; i += stride) {
    const float4* p = (const float4*)in + (size_t)i * 2;
    float4 a = p[0], b4 = p[1];
    s16x8 o;
    o[0] = (short)f2bf(a.x);  o[1] = (short)f2bf(a.y);
    o[2] = (short)f2bf(a.z);  o[3] = (short)f2bf(a.w);
    o[4] = (short)f2bf(b4.x); o[5] = (short)f2bf(b4.y);
    o[6] = (short)f2bf(b4.z); o[7] = (short)f2bf(b4.w);
    *(s16x8*)(out + (size_t)i * 8) = o;
  }
}

// ---------------- mask -> bias (bf16, log2 domain) ----------------
__global__ void bias_k(const int* __restrict__ mask, u16* __restrict__ biasv, int n) {
  const int i = (int)(blockIdx.x * blockDim.x + threadIdx.x);
  if (i < n) biasv[i] = mask[i] ? f2bf(BIAS_VALID) : f2bf(BIAS_MASKED);
}

// ---------------- GEMM: C[m,n] = sum_k A[m,k]*Bw[n,k] ----------------
template <int OUT_MODE>
__global__ __launch_bounds__(256) void gemm_bt_k(const u16* __restrict__ A,
                                                 const u16* __restrict__ Bw,
                                                 void* __restrict__ Cv) {
  constexpr int M = 8192, N = 2048, K = 2048;
  __shared__ u16 As[128 * 64];
  __shared__ u16 Bs[128 * 64];
  const int tid = (int)threadIdx.x;
  const int w = tid >> 6, lane = tid & 63;
  const int l16 = lane & 15, lgrp = lane >> 4;
  const int wr = w >> 1, wc = w & 1;

  const int nwg = (int)gridDim.x;
  const int cpx = nwg >> 3;
  const int bid = (int)blockIdx.x;
  const int sb = (bid & 7) * cpx + (bid >> 3);
  const int bn = sb & 15;
  const int bm = sb >> 4;

  const int srow = w * 32 + (lane >> 3);
  const int scol = (lane & 7) * 8;
  const u16* agp = A  + ((size_t)(bm * 128 + srow)) * K + scol;
  const u16* bgp = Bw + ((size_t)(bn * 128 + srow)) * K + scol;
  u16* alds = &As[w * 2048];
  u16* blds = &Bs[w * 2048];

  const f32x4 zero = {0.f, 0.f, 0.f, 0.f};
  f32x4 acc[4][4];
#pragma unroll
  for (int mi = 0; mi < 4; ++mi)
#pragma unroll
    for (int ni = 0; ni < 4; ++ni) acc[mi][ni] = zero;

  for (int kt = 0; kt < K; kt += 64) {
    __syncthreads();
#pragma unroll
    for (int i = 0; i < 4; ++i) {
      gload16(agp + kt + i * 8 * K, alds + i * 512);
      gload16(bgp + kt + i * 8 * K, blds + i * 512);
    }
    __syncthreads();
#pragma unroll
    for (int sl = 0; sl < 2; ++sl) {
      s16x8 af[4], bfr[4];
#pragma unroll
      for (int mi = 0; mi < 4; ++mi)
        af[mi] = *(const s16x8*)&As[(wr * 64 + mi * 16 + l16) * 64 + sl * 32 + lgrp * 8];
#pragma unroll
      for (int ni = 0; ni < 4; ++ni)
        bfr[ni] = *(const s16x8*)&Bs[(wc * 64 + ni * 16 + l16) * 64 + sl * 32 + lgrp * 8];
#pragma unroll
      for (int mi = 0; mi < 4; ++mi)
#pragma unroll
        for (int ni = 0; ni < 4; ++ni)
          acc[mi][ni] = mfma16(af[mi], bfr[ni], acc[mi][ni]);
    }
  }

  const size_t row0 = (size_t)bm * 128 + wr * 64;
  const size_t col0 = (size_t)bn * 128 + wc * 64;
#pragma unroll
  for (int mi = 0; mi < 4; ++mi)
#pragma unroll
    for (int ni = 0; ni < 4; ++ni) {
      const size_t r0 = row0 + mi * 16 + lgrp * 4;
      const size_t c  = col0 + ni * 16 + l16;
      if constexpr (OUT_MODE == 0) {
        u16* C = (u16*)Cv;
#pragma unroll
        for (int r = 0; r < 4; ++r) C[(r0 + r) * N + c] = f2bf(acc[mi][ni][r]);
      } else if constexpr (OUT_MODE == 1) {
        float* C = (float*)Cv;
#pragma unroll
        for (int r = 0; r < 4; ++r) C[(r0 + r) * N + c] = acc[mi][ni][r];
      } else {
        u16* C = (u16*)Cv;
        s16x4 v;
#pragma unroll
        for (int r = 0; r < 4; ++r) v[r] = (short)f2bf(acc[mi][ni][r]);
        *(s16x4*)&C[c * (size_t)M + r0] = v;
      }
    }
}

// -------- RoPE on q (first 512 dims) + global scale by QK_SCALE_LOG2 --------
__global__ void rope_k(u16* __restrict__ qb, const int* __restrict__ pos_ids) {
  const int row = (int)blockIdx.x;          // b*SEQ + s
  const int s = row & (SEQ - 1);
  const int t = (int)threadIdx.x;           // 0..255
  const float pos = (float)pos_ids[s];
  const float ang = pos * exp2f((float)t * (-13.287712379549449f / 256.0f));
  float sn, cs;
  sincosf(ang, &sn, &cs);
  u16* p = qb + (size_t)row * DMODEL;
  const float x = bf2f(p[t]);
  const float y = bf2f(p[t + 256]);
  p[t]       = f2bf((x * cs - y * sn) * QK_SCALE_LOG2);
  p[t + 256] = f2bf((y * cs + x * sn) * QK_SCALE_LOG2);
#pragma unroll
  for (int j = 0; j < 6; ++j) {
    const int d = 512 + t + 256 * j;
    p[d] = f2bf(bf2f(p[d]) * QK_SCALE_LOG2);
  }
}

// ---------------- flash attention, 32x32 swapped structure ----------------
// q (pre-scaled), k: [B][S][2048] bf16; vt: [2048][NB] bf16 (V^T);
// biasv: [B][S] bf16 (log2-domain, -inf-ish for masked); att: [B][S][2048] bf16.
// One block = 128 q-rows of one (b,g); 4 waves x 32 q-rows.
__device__ __forceinline__ void attn_stage(u16* Ks, u16* Vs,
                                           const u16* kbase, const u16* vbase,
                                           int kt, int w, int lane) {
#pragma unroll
  for (int i = 0; i < 4; ++i) {   // K tile [64][128], 256B rows, XOR-swizzled
    const int row = w * 16 + i * 4 + (lane >> 4);
    const int srcb = ((lane & 15) * 16) ^ ((row & 7) << 4);
    gload16(kbase + (size_t)(kt + row) * DMODEL + (srcb >> 1), &Ks[(w * 16 + i * 4) * 128]);
  }
#pragma unroll
  for (int i = 0; i < 4; ++i) {   // V^T tile [128][64], 128B rows, XOR-swizzled
    const int row = w * 32 + i * 8 + (lane >> 3);
    const int srcb = ((lane & 7) * 16) ^ ((row & 7) << 4);
    gload16(vbase + (size_t)row * NB + kt + (srcb >> 1), &Vs[(w * 32 + i * 8) * 64]);
  }
}

__global__ __launch_bounds__(256) void attn_k(const u16* __restrict__ q,
                                              const u16* __restrict__ k,
                                              const u16* __restrict__ vt,
                                              const u16* __restrict__ biasv,
                                              u16* __restrict__ att) {
  __shared__ u16 Ks[2][64 * 128];
  __shared__ u16 Vs[2][128 * 64];

  const int tid = (int)threadIdx.x;
  const int w = tid >> 6, lane = tid & 63;
  const int l32 = lane & 31, hi = lane >> 5;

  const int bid = (int)blockIdx.x;
  const int sb = (bid & 7) * 128 + (bid >> 3);   // XCD swizzle (1024 wgs)
  const int qt = sb & 15;                         // 2048/128 q-tiles
  const int bg = sb >> 4;
  const int b = bg >> 4, g = bg & 15;

  // Q fragments (B-operand): B[col=q=l32][k=d slice], 8 steps of 16 d
  const int qrow = qt * 128 + w * 32 + l32;
  const u16* qp = q + ((size_t)b * SEQ + qrow) * DMODEL + g * DH;
  s16x8 aq[8];
#pragma unroll
  for (int s = 0; s < 8; ++s) aq[s] = *(const s16x8*)(qp + s * 16 + hi * 8);

  // constant fragments
  const u32 one0 = (hi == 0) ? 0x00003F80u : 0u;
  const s16x8 bones = frag_from_words(one0, 0, 0, 0);            // B: ones at k=0
  const s16x8 allones = frag_from_words(0x3F803F80u, 0x3F803F80u, 0x3F803F80u, 0x3F803F80u);

  f32x16 oacc[4], lacc;
#pragma unroll
  for (int r = 0; r < 16; ++r) {
    lacc[r] = 0.f;
#pragma unroll
    for (int d0 = 0; d0 < 4; ++d0) oacc[d0][r] = 0.f;
  }

  const u16* kbase = k + (size_t)b * SEQ * DMODEL + g * DH;
  const u16* vbase = vt + (size_t)(g * DH) * NB + (size_t)b * SEQ;
  const u16* bbase = biasv + b * SEQ;

  attn_stage(Ks[0], Vs[0], kbase, vbase, 0, w, lane);
  u16 bb0 = bbase[l32], bb1 = bbase[32 + l32];

  for (int t = 0; t < 32; ++t) {
    const int cur = t & 1;
    __syncthreads();   // compiler drains vmcnt here -> tile t ready
    u16 bbn0 = bb0, bbn1 = bb1;
    if (t < 31) {
      attn_stage(Ks[cur ^ 1], Vs[cur ^ 1], kbase, vbase, (t + 1) * 64, w, lane);
      bbn0 = bbase[(t + 1) * 64 + l32];
      bbn1 = bbase[(t + 1) * 64 + 32 + l32];
    }
    const u16* KsC = Ks[cur];
    const u16* VsC = Vs[cur];

    // score init via bias MFMA: sacc[key][q] = bias[key]
    const s16x8 ab0 = frag_from_words((hi == 0) ? (u32)bb0 : 0u, 0, 0, 0);
    const s16x8 ab1 = frag_from_words((hi == 0) ? (u32)bb1 : 0u, 0, 0, 0);
    __builtin_amdgcn_s_setprio(1);
    f32x16 sacc0 = mfma32(ab0, bones, (f32x16)(0.f));
    f32x16 sacc1 = mfma32(ab1, bones, (f32x16)(0.f));

    // QK^T swapped: A=K (row=key), B=Q (col=q)
#pragma unroll
    for (int s = 0; s < 8; ++s) {
      const int byteoff = ((s * 32 + hi * 16) ^ ((l32 & 7) << 4)) >> 1;
      const s16x8 a0 = *(const s16x8*)&KsC[l32 * 128 + byteoff];
      const s16x8 a1 = *(const s16x8*)&KsC[(32 + l32) * 128 + byteoff];
      sacc0 = mfma32(a0, aq[s], sacc0);
      sacc1 = mfma32(a1, aq[s], sacc1);
    }
    __builtin_amdgcn_s_setprio(0);

    // p = exp2(sacc); pack to bf16 pairs (consecutive keys = consecutive words)
    u32 pk0[8], pk1[8];
#pragma unroll
    for (int i = 0; i < 8; ++i) {
      pk0[i] = pack_bf16(EXP2(sacc0[2 * i]), EXP2(sacc0[2 * i + 1]));
      pk1[i] = pack_bf16(EXP2(sacc1[2 * i]), EXP2(sacc1[2 * i + 1]));
    }
    // build P A-frags via permlane32_swap: pa[ks] = P[q=l32][key = ks*16 + hi*8 + j]
    // {w0,w2} = swap(pk[0],pk[2]); {w1,w3} = swap(pk[1],pk[3])  (per 16-key group)
    s16x8 pa[4];
#pragma unroll
    for (int grp = 0; grp < 4; ++grp) {
      u32* pk = (grp < 2) ? pk0 : pk1;
      const int o = (grp & 1) * 4;
      plswap(pk[o + 0], pk[o + 2]);
      plswap(pk[o + 1], pk[o + 3]);
      pa[grp] = frag_from_words(pk[o + 0], pk[o + 1], pk[o + 2], pk[o + 3]);
    }

    // row sums via MFMA with all-ones B (same C layout as oacc)
    __builtin_amdgcn_s_setprio(1);
#pragma unroll
    for (int ks = 0; ks < 4; ++ks) lacc = mfma32(pa[ks], allones, lacc);

    // PV: O[q][d] += P[q][key] @ V[key][d]; B from V^T rows (d), 8 keys each
#pragma unroll
    for (int d0 = 0; d0 < 4; ++d0) {
      const int rowd = d0 * 32 + l32;
#pragma unroll
      for (int ks = 0; ks < 4; ++ks) {
        const int byteoff = ((ks * 32 + hi * 16) ^ ((l32 & 7) << 4)) >> 1;
        const s16x8 bv = *(const s16x8*)&VsC[rowd * 64 + byteoff];
        oacc[d0] = mfma32(pa[ks], bv, oacc[d0]);
      }
    }
    __builtin_amdgcn_s_setprio(0);
    bb0 = bbn0; bb1 = bbn1;
  }

  // epilogue: normalize and store
  float rinv[16];
#pragma unroll
  for (int r = 0; r < 16; ++r) rinv[r] = 1.0f / lacc[r];
  u16* ob = att + ((size_t)b * SEQ + qt * 128 + w * 32) * DMODEL + g * DH;
#pragma unroll
  for (int d0 = 0; d0 < 4; ++d0)
#pragma unroll
    for (int r = 0; r < 16; ++r) {
      const int qloc = (r & 3) + 8 * (r >> 2) + 4 * hi;
      ob[(size_t)qloc * DMODEL + d0 * 32 + l32] = f2bf(oacc[d0][r] * rinv[r]);
    }
}

// ---------------- launch ----------------
extern "C" void kernel_launch(void* const* d_in, const int* in_sizes, int n_in,
                              void* d_out, int out_size, void* d_ws, size_t ws_size,
                              hipStream_t stream) {
  const float* query = (const float*)d_in[0];
  const float* key   = (const float*)d_in[1];
  const float* value = (const float*)d_in[2];
  const int*   maskp = (const int*)d_in[3];
  const int*   posp  = (const int*)d_in[4];
  const float* Wq    = (const float*)d_in[5];
  const float* Wk    = (const float*)d_in[6];
  const float* Wv    = (const float*)d_in[7];
  const float* Wo    = (const float*)d_in[8];

  char* ws = (char*)d_ws;
  const size_t MB = 1024ull * 1024ull;
  u16* wq_b = (u16*)(ws + 0 * MB);
  u16* wk_b = (u16*)(ws + 8 * MB);
  u16* wv_b = (u16*)(ws + 16 * MB);
  u16* wo_b = (u16*)(ws + 24 * MB);
  u16* xq   = (u16*)(ws + 32 * MB);
  u16* xk   = (u16*)(ws + 64 * MB);
  u16* xv   = (u16*)(ws + 96 * MB);
  u16* qb   = (u16*)(ws + 128 * MB);
  u16* kb   = (u16*)(ws + 160 * MB);
  u16* vtb  = (u16*)(ws + 192 * MB);
  u16* att  = xq;                       // xq dead after q-projection
  u16* biasv = xk;                      // xk dead after k-projection

  const int nTok8 = (NBATCH * SEQ * DMODEL) / 8;
  const int nW8   = (DMODEL * DMODEL) / 8;
  cvt_k<<<dim3(2048), dim3(256), 0, stream>>>(query, xq, nTok8);
  cvt_k<<<dim3(2048), dim3(256), 0, stream>>>(key,   xk, nTok8);
  cvt_k<<<dim3(2048), dim3(256), 0, stream>>>(value, xv, nTok8);
  cvt_k<<<dim3(2048), dim3(256), 0, stream>>>(Wq, wq_b, nW8);
  cvt_k<<<dim3(2048), dim3(256), 0, stream>>>(Wk, wk_b, nW8);
  cvt_k<<<dim3(2048), dim3(256), 0, stream>>>(Wv, wv_b, nW8);
  cvt_k<<<dim3(2048), dim3(256), 0, stream>>>(Wo, wo_b, nW8);

  gemm_bt_k<0><<<dim3(1024), dim3(256), 0, stream>>>(xq, wq_b, (void*)qb);
  gemm_bt_k<0><<<dim3(1024), dim3(256), 0, stream>>>(xk, wk_b, (void*)kb);
  gemm_bt_k<2><<<dim3(1024), dim3(256), 0, stream>>>(xv, wv_b, (void*)vtb);

  // xk is dead now: build bias table in its place
  bias_k<<<dim3((NBATCH * SEQ + 255) / 256), dim3(256), 0, stream>>>(maskp, biasv, NBATCH * SEQ);

  rope_k<<<dim3(NBATCH * SEQ), dim3(256), 0, stream>>>(qb, posp);

  attn_k<<<dim3(1024), dim3(256), 0, stream>>>(qb, kb, vtb, biasv, att);

  gemm_bt_k<1><<<dim3(1024), dim3(256), 0, stream>>>(att, wo_b, d_out);

  (void)in_sizes; (void)n_in; (void)out_size; (void)ws_size;
}

// Round 6
// 602.201 us; speedup vs baseline: 1.4315x; 1.2010x over previous
//
#include <hip/hip_runtime.h>
#include <hip/hip_bf16.h>
#include <type_traits>
#include <utility>

typedef unsigned short u16;
typedef unsigned int u32;
typedef __attribute__((ext_vector_type(8))) short  s16x8;
typedef __attribute__((ext_vector_type(4))) short  s16x4;
typedef __attribute__((ext_vector_type(4))) float  f32x4;
typedef __attribute__((ext_vector_type(16))) float f32x16;
typedef __bf16 bf16x8_t __attribute__((ext_vector_type(8)));
typedef __bf16 bf16x2_t __attribute__((ext_vector_type(2)));

#define SEQ 2048
#define DMODEL 2048
#define NBATCH 4
#define DH 128
#define NB (NBATCH * SEQ)

// Q pre-scale: (1/sqrt(128)) * log2(e)  -> scores come out in log2 domain
#define QK_SCALE_LOG2 0.12754375f
// bias constants (log2 domain): valid = -24*log2e ; masked = huge negative
#define BIAS_VALID  (-34.624681f)
#define BIAS_MASKED (-180.0f)

#if __has_builtin(__builtin_amdgcn_exp2f)
#define EXP2(x) __builtin_amdgcn_exp2f(x)
#else
#define EXP2(x) exp2f(x)
#endif

#define BARRIER __builtin_amdgcn_s_barrier()
#define FENCE asm volatile("" ::: "memory")
#define VMCNT8 asm volatile("s_waitcnt vmcnt(8)" ::: "memory")
#define VMCNT0 asm volatile("s_waitcnt vmcnt(0)" ::: "memory")

static __device__ __forceinline__ u16 f2bf(float f) {
  unsigned u = __float_as_uint(f);
  u += 0x7fffu + ((u >> 16) & 1u);
  return (u16)(u >> 16);
}
static __device__ __forceinline__ float bf2f(u16 h) {
  return __uint_as_float(((unsigned)h) << 16);
}
static __device__ __forceinline__ u32 pack_bf16(float a, float b) {
  bf16x2_t t; t[0] = (__bf16)a; t[1] = (__bf16)b;
  return __builtin_bit_cast(u32, t);
}
// v_permlane32_swap_b32: after the op, a = {a.row0, b.row0}, b = {a.row1, b.row1}
static __device__ __forceinline__ void plswap(u32& a, u32& b) {
  asm("v_permlane32_swap_b32 %0, %1" : "+v"(a), "+v"(b));
}

// ---- MFMA wrappers: robust to short8 vs bf16x8 builtin signature ----
template <typename T, typename = void>
struct mfma_takes : std::false_type {};
template <typename T>
struct mfma_takes<T, std::void_t<decltype(__builtin_amdgcn_mfma_f32_16x16x32_bf16(
    std::declval<T>(), std::declval<T>(), std::declval<f32x4>(), 0, 0, 0))>>
    : std::true_type {};
using mfma_frag_t = std::conditional_t<mfma_takes<s16x8>::value, s16x8, bf16x8_t>;

static __device__ __forceinline__ f32x16 mfma32(s16x8 a, s16x8 b, f32x16 c) {
  return __builtin_amdgcn_mfma_f32_32x32x16_bf16(
      __builtin_bit_cast(mfma_frag_t, a), __builtin_bit_cast(mfma_frag_t, b), c, 0, 0, 0);
}

typedef const void __attribute__((address_space(1)))* gas_ptr;
typedef void __attribute__((address_space(3)))* las_ptr;
static __device__ __forceinline__ void gload16(const void* g, void* l) {
  __builtin_amdgcn_global_load_lds((gas_ptr)g, (las_ptr)l, 16, 0, 0);
}

static __device__ __forceinline__ s16x8 frag_from_words(u32 w0, u32 w1, u32 w2, u32 w3) {
  union { u32 w[4]; s16x8 v; } u;
  u.w[0] = w0; u.w[1] = w1; u.w[2] = w2; u.w[3] = w3;
  return u.v;
}

// ---------------- f32 -> bf16 converts (batched) ----------------
static __device__ __forceinline__ void cvt8(const float* src, u16* dst, int i) {
  const float4* p = (const float4*)src + (size_t)i * 2;
  float4 a = p[0], b4 = p[1];
  s16x8 o;
  o[0] = (short)f2bf(a.x);  o[1] = (short)f2bf(a.y);
  o[2] = (short)f2bf(a.z);  o[3] = (short)f2bf(a.w);
  o[4] = (short)f2bf(b4.x); o[5] = (short)f2bf(b4.y);
  o[6] = (short)f2bf(b4.z); o[7] = (short)f2bf(b4.w);
  *(s16x8*)(dst + (size_t)i * 8) = o;
}

__global__ void cvt3_k(const float* __restrict__ a, const float* __restrict__ b,
                       const float* __restrict__ c, u16* __restrict__ oa,
                       u16* __restrict__ ob, u16* __restrict__ oc) {
  const int n8 = 1 << 21;   // per-segment float8 count
  const int stride = (int)(gridDim.x * blockDim.x);
  for (int i = (int)(blockIdx.x * blockDim.x + threadIdx.x); i < 3 * n8; i += stride) {
    const int seg = i >> 21, off = i & (n8 - 1);
    const float* src = seg == 0 ? a : (seg == 1 ? b : c);
    u16* dst = seg == 0 ? oa : (seg == 1 ? ob : oc);
    cvt8(src, dst, off);
  }
}

__global__ void cvt4_k(const float* __restrict__ a, const float* __restrict__ b,
                       const float* __restrict__ c, const float* __restrict__ d,
                       u16* __restrict__ oa, u16* __restrict__ ob,
                       u16* __restrict__ oc, u16* __restrict__ od) {
  const int n8 = 1 << 19;
  const int stride = (int)(gridDim.x * blockDim.x);
  for (int i = (int)(blockIdx.x * blockDim.x + threadIdx.x); i < 4 * n8; i += stride) {
    const int seg = i >> 19, off = i & (n8 - 1);
    const float* src = seg == 0 ? a : (seg == 1 ? b : (seg == 2 ? c : d));
    u16* dst = seg == 0 ? oa : (seg == 1 ? ob : (seg == 2 ? oc : od));
    cvt8(src, dst, off);
  }
}

// ---------------- mask -> bias (bf16, log2 domain) ----------------
__global__ void bias_k(const int* __restrict__ mask, u16* __restrict__ biasv, int n) {
  const int i = (int)(blockIdx.x * blockDim.x + threadIdx.x);
  if (i < n) biasv[i] = mask[i] ? f2bf(BIAS_VALID) : f2bf(BIAS_MASKED);
}

// ======== 256x256 GEMM, full-tile prefetch + deferred counted vmcnt ========
// A: [8192][2048] bf16, Bw: [2048][2048] bf16 (both K-contiguous).
// 8 waves (2Mx4N), BK=64, dbuf LDS (128 KiB), XOR-swizzle (row&7)<<4 both-sides.
// Schedule: STAGE8(t+1) -> vmcnt(8) [completes tile-t loads issued a full
// iteration earlier -> near-free] -> barrier -> 4 fence-pinned quadrant
// phases (ds_read + setprio MFMA) -> barrier (protects buffer reuse).
// OUT_MODE 0: bf16 C[m][n]; 1: f32 C[m][n]; 2: bf16 C^T[n][m].
template <int OUT_MODE>
__global__ __launch_bounds__(512, 2) void gemm256_k(const u16* __restrict__ A,
                                                    const u16* __restrict__ Bw,
                                                    void* __restrict__ Cv) {
  constexpr int M = 8192, N = 2048, K = 2048;
  constexpr int NT = K / 64;
  __shared__ u16 Ab[2][256 * 64];
  __shared__ u16 Bb[2][256 * 64];

  const int tid = (int)threadIdx.x;
  const int wv = tid >> 6, lane = tid & 63;
  const int l32 = lane & 31, hi = lane >> 5;
  const int wm = wv >> 2, wn = wv & 3;

  // XCD swizzle: 256 blocks = 32 bm x 8 bn (256 % 8 == 0 -> bijective)
  const int bid = (int)blockIdx.x;
  const int sb = (bid & 7) * 32 + (bid >> 3);
  const int bn = sb & 7, bm = sb >> 3;

  const size_t arow0 = (size_t)bm * 256;
  const size_t brow0 = (size_t)bn * 256;

  // staging: 512 threads x 16B = 64 rows per gload instruction
  const int srow = tid >> 3;            // 0..63 within a 64-row chunk
  const int scolb = (tid & 7) * 16;     // byte col within 128B row
  const int scol = (scolb ^ ((srow & 7) << 4)) >> 1;  // pre-swizzled src col (elems)
  const u16* agp = A  + (arow0 + srow) * (size_t)K + scol;
  const u16* bgp = Bw + (brow0 + srow) * (size_t)K + scol;

  f32x16 acc[4][2];
#pragma unroll
  for (int mi = 0; mi < 4; ++mi)
#pragma unroll
    for (int ni = 0; ni < 2; ++ni)
#pragma unroll
      for (int r = 0; r < 16; ++r) acc[mi][ni][r] = 0.f;

  // full-tile stage: 8 gloads (wave-uniform LDS dest, per-lane swizzled source)
  auto STAGE8 = [&](int kt2, u16* bufA, u16* bufB) {
#pragma unroll
    for (int j = 0; j < 4; ++j)
      gload16(agp + (size_t)(j * 64) * K + kt2, bufA + (j * 64 + wv * 8) * 64);
#pragma unroll
    for (int j = 0; j < 4; ++j)
      gload16(bgp + (size_t)(j * 64) * K + kt2, bufB + (j * 64 + wv * 8) * 64);
  };
  auto LDA = [&](const u16* buf, int qm, s16x8* af) {
#pragma unroll
    for (int mb = 0; mb < 2; ++mb) {
      const int row = wm * 128 + qm * 64 + mb * 32 + l32;
#pragma unroll
      for (int ks = 0; ks < 4; ++ks) {
        const int cb = ((ks * 32 + hi * 16) ^ ((row & 7) << 4)) >> 1;
        af[mb * 4 + ks] = *(const s16x8*)&buf[row * 64 + cb];
      }
    }
  };
  auto LDB = [&](const u16* buf, int qn, s16x8* bfr) {
    const int row = wn * 64 + qn * 32 + l32;
#pragma unroll
    for (int ks = 0; ks < 4; ++ks) {
      const int cb = ((ks * 32 + hi * 16) ^ ((row & 7) << 4)) >> 1;
      bfr[ks] = *(const s16x8*)&buf[row * 64 + cb];
    }
  };
  auto MM = [&](const s16x8* af, const s16x8* bfr, int qm, int qn) {
    __builtin_amdgcn_s_setprio(1);
#pragma unroll
    for (int mb = 0; mb < 2; ++mb)
#pragma unroll
      for (int ks = 0; ks < 4; ++ks)
        acc[qm * 2 + mb][qn] = mfma32(af[mb * 4 + ks], bfr[ks], acc[qm * 2 + mb][qn]);
    __builtin_amdgcn_s_setprio(0);
  };

  STAGE8(0, Ab[0], Bb[0]);

  for (int t = 0; t < NT; ++t) {
    u16* Ac = Ab[t & 1];
    u16* Bc = Bb[t & 1];
    if (t < NT - 1) {
      STAGE8((t + 1) * 64, Ab[(t + 1) & 1], Bb[(t + 1) & 1]);
      VMCNT8;          // completes tile-t's 8 loads (issued 1 iteration ago)
    } else {
      VMCNT0;
    }
    BARRIER; FENCE;
    s16x8 af0[8], af1[8], bf0[4], bf1[4];
    // quadrant order (0,0)->(0,1)->(1,1)->(1,0): max fragment reuse
    LDA(Ac, 0, af0); LDB(Bc, 0, bf0);
    MM(af0, bf0, 0, 0);
    FENCE;
    LDB(Bc, 1, bf1);
    MM(af0, bf1, 0, 1);
    FENCE;
    LDA(Ac, 1, af1);
    MM(af1, bf1, 1, 1);
    FENCE;
    MM(af1, bf0, 1, 0);
    BARRIER; FENCE;    // all reads done before next STAGE8 overwrites buf[t&1]
  }

  // epilogue: C row = rbase + 8*q + rr (reg = q*4+rr), col = l32-based
  const size_t row0 = arow0 + (size_t)wm * 128;
  const size_t col0 = brow0 + (size_t)wn * 64;
#pragma unroll
  for (int mi = 0; mi < 4; ++mi)
#pragma unroll
    for (int ni = 0; ni < 2; ++ni) {
      const size_t rbase = row0 + mi * 32 + 4 * hi;
      const size_t c = col0 + ni * 32 + l32;
      if constexpr (OUT_MODE == 0) {
        u16* C = (u16*)Cv;
#pragma unroll
        for (int q = 0; q < 4; ++q)
#pragma unroll
          for (int rr = 0; rr < 4; ++rr)
            C[(rbase + 8 * q + rr) * N + c] = f2bf(acc[mi][ni][q * 4 + rr]);
      } else if constexpr (OUT_MODE == 1) {
        float* C = (float*)Cv;
#pragma unroll
        for (int q = 0; q < 4; ++q)
#pragma unroll
          for (int rr = 0; rr < 4; ++rr)
            C[(rbase + 8 * q + rr) * N + c] = acc[mi][ni][q * 4 + rr];
      } else {
        u16* C = (u16*)Cv;
#pragma unroll
        for (int q = 0; q < 4; ++q) {
          s16x4 v;
#pragma unroll
          for (int rr = 0; rr < 4; ++rr) v[rr] = (short)f2bf(acc[mi][ni][q * 4 + rr]);
          *(s16x4*)&C[c * (size_t)M + rbase + 8 * q] = v;   // C^T[n][m]
        }
      }
    }
}

// -------- RoPE on q (first 512 dims) + global scale by QK_SCALE_LOG2 --------
__global__ void rope_k(u16* __restrict__ qb, const int* __restrict__ pos_ids) {
  const int row = (int)blockIdx.x;          // b*SEQ + s
  const int s = row & (SEQ - 1);
  const int t = (int)threadIdx.x;           // 0..255
  const float pos = (float)pos_ids[s];
  const float ang = pos * exp2f((float)t * (-13.287712379549449f / 256.0f));
  float sn, cs;
  sincosf(ang, &sn, &cs);
  u16* p = qb + (size_t)row * DMODEL;
  const float x = bf2f(p[t]);
  const float y = bf2f(p[t + 256]);
  p[t]       = f2bf((x * cs - y * sn) * QK_SCALE_LOG2);
  p[t + 256] = f2bf((y * cs + x * sn) * QK_SCALE_LOG2);
#pragma unroll
  for (int j = 0; j < 6; ++j) {
    const int d = 512 + t + 256 * j;
    p[d] = f2bf(bf2f(p[d]) * QK_SCALE_LOG2);
  }
}

// ---------------- flash attention, 32x32 swapped structure ----------------
__device__ __forceinline__ void attn_stage(u16* Ks, u16* Vs,
                                           const u16* kbase, const u16* vbase,
                                           int kt, int w, int lane) {
#pragma unroll
  for (int i = 0; i < 4; ++i) {   // K tile [64][128], 256B rows, XOR-swizzled
    const int row = w * 16 + i * 4 + (lane >> 4);
    const int srcb = ((lane & 15) * 16) ^ ((row & 7) << 4);
    gload16(kbase + (size_t)(kt + row) * DMODEL + (srcb >> 1), &Ks[(w * 16 + i * 4) * 128]);
  }
#pragma unroll
  for (int i = 0; i < 4; ++i) {   // V^T tile [128][64], 128B rows, XOR-swizzled
    const int row = w * 32 + i * 8 + (lane >> 3);
    const int srcb = ((lane & 7) * 16) ^ ((row & 7) << 4);
    gload16(vbase + (size_t)row * NB + kt + (srcb >> 1), &Vs[(w * 32 + i * 8) * 64]);
  }
}

__global__ __launch_bounds__(256) void attn_k(const u16* __restrict__ q,
                                              const u16* __restrict__ k,
                                              const u16* __restrict__ vt,
                                              const u16* __restrict__ biasv,
                                              u16* __restrict__ att) {
  __shared__ u16 Ks[2][64 * 128];
  __shared__ u16 Vs[2][128 * 64];

  const int tid = (int)threadIdx.x;
  const int w = tid >> 6, lane = tid & 63;
  const int l32 = lane & 31, hi = lane >> 5;

  const int bid = (int)blockIdx.x;
  const int sb = (bid & 7) * 128 + (bid >> 3);   // XCD swizzle (1024 wgs)
  const int qt = sb & 15;
  const int bg = sb >> 4;
  const int b = bg >> 4, g = bg & 15;

  const int qrow = qt * 128 + w * 32 + l32;
  const u16* qp = q + ((size_t)b * SEQ + qrow) * DMODEL + g * DH;
  s16x8 aq[8];
#pragma unroll
  for (int s = 0; s < 8; ++s) aq[s] = *(const s16x8*)(qp + s * 16 + hi * 8);

  const u32 one0 = (hi == 0) ? 0x00003F80u : 0u;
  const s16x8 bones = frag_from_words(one0, 0, 0, 0);
  const s16x8 allones = frag_from_words(0x3F803F80u, 0x3F803F80u, 0x3F803F80u, 0x3F803F80u);

  f32x16 oacc[4], lacc;
#pragma unroll
  for (int r = 0; r < 16; ++r) {
    lacc[r] = 0.f;
#pragma unroll
    for (int d0 = 0; d0 < 4; ++d0) oacc[d0][r] = 0.f;
  }

  const u16* kbase = k + (size_t)b * SEQ * DMODEL + g * DH;
  const u16* vbase = vt + (size_t)(g * DH) * NB + (size_t)b * SEQ;
  const u16* bbase = biasv + b * SEQ;

  attn_stage(Ks[0], Vs[0], kbase, vbase, 0, w, lane);
  u16 bb0 = bbase[l32], bb1 = bbase[32 + l32];

  for (int t = 0; t < 32; ++t) {
    const int cur = t & 1;
    __syncthreads();
    u16 bbn0 = bb0, bbn1 = bb1;
    if (t < 31) {
      attn_stage(Ks[cur ^ 1], Vs[cur ^ 1], kbase, vbase, (t + 1) * 64, w, lane);
      bbn0 = bbase[(t + 1) * 64 + l32];
      bbn1 = bbase[(t + 1) * 64 + 32 + l32];
    }
    const u16* KsC = Ks[cur];
    const u16* VsC = Vs[cur];

    const s16x8 ab0 = frag_from_words((hi == 0) ? (u32)bb0 : 0u, 0, 0, 0);
    const s16x8 ab1 = frag_from_words((hi == 0) ? (u32)bb1 : 0u, 0, 0, 0);
    __builtin_amdgcn_s_setprio(1);
    f32x16 sacc0 = mfma32(ab0, bones, (f32x16)(0.f));
    f32x16 sacc1 = mfma32(ab1, bones, (f32x16)(0.f));

#pragma unroll
    for (int s = 0; s < 8; ++s) {
      const int byteoff = ((s * 32 + hi * 16) ^ ((l32 & 7) << 4)) >> 1;
      const s16x8 a0 = *(const s16x8*)&KsC[l32 * 128 + byteoff];
      const s16x8 a1 = *(const s16x8*)&KsC[(32 + l32) * 128 + byteoff];
      sacc0 = mfma32(a0, aq[s], sacc0);
      sacc1 = mfma32(a1, aq[s], sacc1);
    }
    __builtin_amdgcn_s_setprio(0);

    u32 pk0[8], pk1[8];
#pragma unroll
    for (int i = 0; i < 8; ++i) {
      pk0[i] = pack_bf16(EXP2(sacc0[2 * i]), EXP2(sacc0[2 * i + 1]));
      pk1[i] = pack_bf16(EXP2(sacc1[2 * i]), EXP2(sacc1[2 * i + 1]));
    }
    s16x8 pa[4];
#pragma unroll
    for (int grp = 0; grp < 4; ++grp) {
      u32* pk = (grp < 2) ? pk0 : pk1;
      const int o = (grp & 1) * 4;
      plswap(pk[o + 0], pk[o + 2]);
      plswap(pk[o + 1], pk[o + 3]);
      pa[grp] = frag_from_words(pk[o + 0], pk[o + 1], pk[o + 2], pk[o + 3]);
    }

    __builtin_amdgcn_s_setprio(1);
#pragma unroll
    for (int ks = 0; ks < 4; ++ks) lacc = mfma32(pa[ks], allones, lacc);

#pragma unroll
    for (int d0 = 0; d0 < 4; ++d0) {
      const int rowd = d0 * 32 + l32;
#pragma unroll
      for (int ks = 0; ks < 4; ++ks) {
        const int byteoff = ((ks * 32 + hi * 16) ^ ((rowd & 7) << 4)) >> 1;
        const s16x8 bv = *(const s16x8*)&VsC[rowd * 64 + byteoff];
        oacc[d0] = mfma32(pa[ks], bv, oacc[d0]);
      }
    }
    __builtin_amdgcn_s_setprio(0);
    bb0 = bbn0; bb1 = bbn1;
  }

  float rinv[16];
#pragma unroll
  for (int r = 0; r < 16; ++r) rinv[r] = 1.0f / lacc[r];
  u16* ob = att + ((size_t)b * SEQ + qt * 128 + w * 32) * DMODEL + g * DH;
#pragma unroll
  for (int d0 = 0; d0 < 4; ++d0)
#pragma unroll
    for (int r = 0; r < 16; ++r) {
      const int qloc = (r & 3) + 8 * (r >> 2) + 4 * hi;
      ob[(size_t)qloc * DMODEL + d0 * 32 + l32] = f2bf(oacc[d0][r] * rinv[r]);
    }
}

// ---------------- launch ----------------
extern "C" void kernel_launch(void* const* d_in, const int* in_sizes, int n_in,
                              void* d_out, int out_size, void* d_ws, size_t ws_size,
                              hipStream_t stream) {
  const float* query = (const float*)d_in[0];
  const float* key   = (const float*)d_in[1];
  const float* value = (const float*)d_in[2];
  const int*   maskp = (const int*)d_in[3];
  const int*   posp  = (const int*)d_in[4];
  const float* Wq    = (const float*)d_in[5];
  const float* Wk    = (const float*)d_in[6];
  const float* Wv    = (const float*)d_in[7];
  const float* Wo    = (const float*)d_in[8];

  char* ws = (char*)d_ws;
  const size_t MB = 1024ull * 1024ull;
  u16* wq_b = (u16*)(ws + 0 * MB);
  u16* wk_b = (u16*)(ws + 8 * MB);
  u16* wv_b = (u16*)(ws + 16 * MB);
  u16* wo_b = (u16*)(ws + 24 * MB);
  u16* xq   = (u16*)(ws + 32 * MB);
  u16* xk   = (u16*)(ws + 64 * MB);
  u16* xv   = (u16*)(ws + 96 * MB);
  u16* qb   = (u16*)(ws + 128 * MB);
  u16* kb   = (u16*)(ws + 160 * MB);
  u16* vtb  = (u16*)(ws + 192 * MB);
  u16* att  = xq;                       // xq dead after q-projection
  u16* biasv = xk;                      // xk dead after k-projection

  cvt3_k<<<dim3(2048), dim3(256), 0, stream>>>(query, key, value, xq, xk, xv);
  cvt4_k<<<dim3(1024), dim3(256), 0, stream>>>(Wq, Wk, Wv, Wo, wq_b, wk_b, wv_b, wo_b);

  gemm256_k<0><<<dim3(256), dim3(512), 0, stream>>>(xq, wq_b, (void*)qb);
  gemm256_k<0><<<dim3(256), dim3(512), 0, stream>>>(xk, wk_b, (void*)kb);
  gemm256_k<2><<<dim3(256), dim3(512), 0, stream>>>(xv, wv_b, (void*)vtb);

  bias_k<<<dim3((NBATCH * SEQ + 255) / 256), dim3(256), 0, stream>>>(maskp, biasv, NBATCH * SEQ);

  rope_k<<<dim3(NBATCH * SEQ), dim3(256), 0, stream>>>(qb, posp);

  attn_k<<<dim3(1024), dim3(256), 0, stream>>>(qb, kb, vtb, biasv, att);

  gemm256_k<1><<<dim3(256), dim3(512), 0, stream>>>(att, wo_b, d_out);

  (void)in_sizes; (void)n_in; (void)out_size; (void)ws_size;
}